// Round 2
// baseline (273.834 us; speedup 1.0000x reference)
//
#include <hip/hip_runtime.h>
#include <cstdint>
#include <cstddef>

#define NROWS 8192
#define DIM   25
#define CIN   128
#define COUT  128
#define MAXT  160

// ---------------- compile-time path tables (mirrors reference _build_paths) --
struct Tables {
  int   w_idx[MAXT];     // per original entry t: weight row
  float coef[MAXT];      // per original entry t: signed coefficient
  int   o_start[DIM + 1];
  int   e_in[MAXT];      // bucketed-by-o: input DIM row
  int   e_t[MAXT];       // bucketed-by-o: original entry index (row of Bt)
  int   T;
};

constexpr Tables build_tables() {
  Tables tb{};
  int off[5] = {0, 1, 4, 9, 16};
  const float pn = 0.44721359549995793f;  // 1/sqrt(5)
  int in_idx[MAXT] = {}, out_idx[MAXT] = {}, widx[MAXT] = {};
  float cf[MAXT] = {};
  int T = 0, w = 0;
  for (int lo = 0; lo < 5; ++lo) {
    for (int li = 0; li < 5; ++li) {
      int oi = off[li], oo = off[lo];
      in_idx[T] = oi + li; out_idx[T] = oo + lo; widx[T] = w; cf[T] = pn; ++T; ++w;
      int mm = li < lo ? li : lo;
      for (int m = 1; m <= mm; ++m) {
        int ip = oi + li + m, im = oi + li - m;
        int op = oo + lo + m, om = oo + lo - m;
        int wre = w, wim = w + 1; w += 2;
        in_idx[T] = ip; out_idx[T] = op; widx[T] = wre; cf[T] = pn;  ++T;
        in_idx[T] = im; out_idx[T] = om; widx[T] = wre; cf[T] = pn;  ++T;
        in_idx[T] = ip; out_idx[T] = om; widx[T] = wim; cf[T] = pn;  ++T;
        in_idx[T] = im; out_idx[T] = op; widx[T] = wim; cf[T] = -pn; ++T;
      }
    }
  }
  tb.T = T;  // 145
  for (int t = 0; t < T; ++t) { tb.w_idx[t] = widx[t]; tb.coef[t] = cf[t]; }
  int pos = 0;
  for (int o = 0; o < DIM; ++o) {
    tb.o_start[o] = pos;
    for (int t = 0; t < T; ++t)
      if (out_idx[t] == o) { tb.e_in[pos] = in_idx[t]; tb.e_t[pos] = t; ++pos; }
  }
  tb.o_start[DIM] = pos;
  return tb;
}

__constant__ Tables TAB = build_tables();

// ---------------- helpers ----------------------------------------------------
__device__ __forceinline__ uint16_t f2bf(float f) {
  uint32_t u = __float_as_uint(f);
  uint32_t r = (u + 0x7FFFu + ((u >> 16) & 1u)) >> 16;
  return (uint16_t)r;
}

__device__ __forceinline__ void load_lds16(const void* g, void* l) {
  __builtin_amdgcn_global_load_lds(
      (const __attribute__((address_space(1))) uint32_t*)g,
      (__attribute__((address_space(3))) uint32_t*)l, 16, 0, 0);
}

typedef __bf16 v8bf __attribute__((ext_vector_type(8)));
typedef float  v4f  __attribute__((ext_vector_type(4)));

// ---------------- kernel 1: fused prep ---------------------------------------
// blocks [0, NCVT): fp32 -> bf16 cast of input (float4 per thread)
// blocks [NCVT, NCVT+145): Bt[t][d][c] = coef[t] * W[w_idx[t]][c][d]  (bf16)
#define NCVT (NROWS * DIM * CIN / 4 / 256)   // 25600 blocks

__global__ void prep_kernel(const float* __restrict__ X, uint16_t* __restrict__ Y,
                            const float* __restrict__ W, uint16_t* __restrict__ Bt) {
  if (blockIdx.x < NCVT) {
    int i = blockIdx.x * 256 + threadIdx.x;
    float4 v = ((const float4*)X)[i];
    ushort4 o;
    o.x = f2bf(v.x); o.y = f2bf(v.y); o.z = f2bf(v.z); o.w = f2bf(v.w);
    ((ushort4*)Y)[i] = o;
  } else {
    int t = blockIdx.x - NCVT;
    int w = TAB.w_idx[t];
    float cf = TAB.coef[t];
    const float* Wp = W + (size_t)w * CIN * COUT;
    uint16_t* Bp = Bt + (size_t)t * CIN * COUT;
    for (int idx = threadIdx.x; idx < CIN * COUT; idx += blockDim.x) {
      int d = idx >> 7, c = idx & 127;
      Bp[idx] = f2bf(cf * Wp[(size_t)c * COUT + d]);  // idx == d*128 + c
    }
  }
}

// ---------------- kernel 2: main GEMM ----------------------------------------
// Per block: output tile Out[n0..n0+127][o][0..127] = sum over entries e of
//   Xb[n][IN[e]][:] (128 ch) . Bt[e_t][:][:]  (K = 128*nE)
// m97 structure: 128x128 tile, 4 waves, BK=64, global_load_lds(16B),
// XOR chunk swizzle so ds_read_b128 frag loads are <=2-way bank conflicted.
// Grid is 1-D with XCD-aware swizzle: XCD = lb&7 gets 8 whole n-tiles; the
// 25 o-blocks of one n-tile run consecutively on one XCD so the 0.8 MB A slab
// is fetched once into that XCD's L2 and reused 25x.
__global__ __launch_bounds__(256) void so2_gemm(
    const uint16_t* __restrict__ Xb,   // [NROWS][DIM][CIN] bf16 bits
    const uint16_t* __restrict__ Bt,   // [T][COUT][CIN]    bf16 bits
    float* __restrict__ Out) {         // [NROWS][DIM][COUT]
  __shared__ __align__(16) uint16_t As[128 * 64];
  __shared__ __align__(16) uint16_t Bs[128 * 64];

  // XCD-aware decode: lb -> (o, n-tile)
  const int lb   = blockIdx.x;            // 0..1599
  const int xcd  = lb & 7;
  const int slot = lb >> 3;               // 0..199
  const int o    = slot % 25;             // o sweeps fastest within an XCD
  const int nt   = xcd + ((slot / 25) << 3);
  const int n0   = nt << 7;

  const int e0 = TAB.o_start[o];
  const int nE = TAB.o_start[o + 1] - e0;

  const int tid  = threadIdx.x;
  const int w    = tid >> 6;
  const int l    = tid & 63;

  // staging geometry: per issue j, rows m = j*32 + srow, LDS slot = l%8,
  // global source chunk = slot ^ (m%8)   (m%8 == l>>3 here)
  const int srow = (w << 3) + (l >> 3);          // 0..31
  const int slt  = l & 7;
  const int ssrc = ((slt ^ (l >> 3)) << 3);      // element offset 0..56

  // compute geometry
  const int lr   = l & 15;
  const int quad = l >> 4;
  const int wr   = (w & 1) << 6;
  const int wc   = (w >> 1) << 6;

  v4f acc[4][4];
  #pragma unroll
  for (int i = 0; i < 4; ++i)
    #pragma unroll
    for (int j = 0; j < 4; ++j)
      acc[i][j] = v4f{0.f, 0.f, 0.f, 0.f};

  const int nIter = nE << 1;
  for (int ki = 0; ki < nIter; ++ki) {
    const int e    = e0 + (ki >> 1);
    const int kk   = (ki & 1) << 6;            // channel half: 0 or 64
    const int irow = TAB.e_in[e];
    const int trow = TAB.e_t[e];

    const uint16_t* gA = Xb + ((size_t)(n0 + srow) * DIM + irow) * CIN + kk + ssrc;
    const uint16_t* gB = Bt + ((size_t)trow * COUT + srow) * CIN + kk + ssrc;

    if (ki) __syncthreads();                    // prev compute done reading LDS
    #pragma unroll
    for (int j = 0; j < 4; ++j) {
      const int m = (j << 5) + srow;
      load_lds16(gA + (size_t)(j << 5) * (DIM * CIN), &As[m * 64 + slt * 8]);
      load_lds16(gB + (size_t)(j << 5) * CIN,         &Bs[m * 64 + slt * 8]);
    }
    __syncthreads();                            // staging visible

    #pragma unroll
    for (int kk2 = 0; kk2 < 2; ++kk2) {
      const int s = (((kk2 << 2) + quad) ^ (lr & 7)) << 3;
      v8bf a[4], b[4];
      #pragma unroll
      for (int i = 0; i < 4; ++i) {
        a[i] = *(const v8bf*)(&As[(wr + (i << 4) + lr) * 64 + s]);
        b[i] = *(const v8bf*)(&Bs[(wc + (i << 4) + lr) * 64 + s]);
      }
      #pragma unroll
      for (int i = 0; i < 4; ++i)
        #pragma unroll
        for (int j = 0; j < 4; ++j)
          acc[i][j] = __builtin_amdgcn_mfma_f32_16x16x32_bf16(a[i], b[j],
                                                              acc[i][j], 0, 0, 0);
    }
  }

  // epilogue: C/D layout col = lane&15 (d), row = quad*4 + r (n)
  #pragma unroll
  for (int i = 0; i < 4; ++i) {
    #pragma unroll
    for (int r = 0; r < 4; ++r) {
      const int n = n0 + wr + (i << 4) + (quad << 2) + r;
      float* op = Out + ((size_t)n * DIM + o) * COUT + wc + lr;
      #pragma unroll
      for (int j = 0; j < 4; ++j)
        op[j << 4] = acc[i][j][r];
    }
  }
}

// ---------------- launcher ---------------------------------------------------
extern "C" void kernel_launch(void* const* d_in, const int* in_sizes, int n_in,
                              void* d_out, int out_size, void* d_ws, size_t ws_size,
                              hipStream_t stream) {
  const float* X = (const float*)d_in[0];   // [8192][25][128]
  const float* W = (const float*)d_in[1];   // [85][128][128]
  float* Out = (float*)d_out;

  uint16_t* Xb = (uint16_t*)d_ws;                                   // 52.4 MB
  uint16_t* Bt = (uint16_t*)((char*)d_ws + (size_t)NROWS * DIM * CIN * 2);  // 4.75 MB

  // 1) fused prep: input fp32->bf16 cast + weight gather/scale/transpose
  prep_kernel<<<NCVT + 145, 256, 0, stream>>>(X, Xb, W, Bt);
  // 2) grouped GEMM, XCD-swizzled 1-D grid
  so2_gemm<<<DIM * (NROWS / 128), 256, 0, stream>>>(Xb, Bt, Out);
}

// Round 3
// 235.551 us; speedup vs baseline: 1.1625x; 1.1625x over previous
//
#include <hip/hip_runtime.h>
#include <cstdint>
#include <cstddef>

#define NROWS 8192
#define DIM   25
#define CIN   128
#define COUT  128
#define MAXT  160

// ---------------- compile-time path tables (mirrors reference _build_paths) --
struct Tables {
  int   w_idx[MAXT];     // per original entry t: weight row
  float coef[MAXT];      // per original entry t: signed coefficient
  int   o_start[DIM + 1];
  int   e_in[MAXT];      // bucketed-by-o: input DIM row
  int   e_t[MAXT];       // bucketed-by-o: original entry index (row of Bt)
  int   T;
};

constexpr Tables build_tables() {
  Tables tb{};
  int off[5] = {0, 1, 4, 9, 16};
  const float pn = 0.44721359549995793f;  // 1/sqrt(5)
  int in_idx[MAXT] = {}, out_idx[MAXT] = {}, widx[MAXT] = {};
  float cf[MAXT] = {};
  int T = 0, w = 0;
  for (int lo = 0; lo < 5; ++lo) {
    for (int li = 0; li < 5; ++li) {
      int oi = off[li], oo = off[lo];
      in_idx[T] = oi + li; out_idx[T] = oo + lo; widx[T] = w; cf[T] = pn; ++T; ++w;
      int mm = li < lo ? li : lo;
      for (int m = 1; m <= mm; ++m) {
        int ip = oi + li + m, im = oi + li - m;
        int op = oo + lo + m, om = oo + lo - m;
        int wre = w, wim = w + 1; w += 2;
        in_idx[T] = ip; out_idx[T] = op; widx[T] = wre; cf[T] = pn;  ++T;
        in_idx[T] = im; out_idx[T] = om; widx[T] = wre; cf[T] = pn;  ++T;
        in_idx[T] = ip; out_idx[T] = om; widx[T] = wim; cf[T] = pn;  ++T;
        in_idx[T] = im; out_idx[T] = op; widx[T] = wim; cf[T] = -pn; ++T;
      }
    }
  }
  tb.T = T;  // 145
  for (int t = 0; t < T; ++t) { tb.w_idx[t] = widx[t]; tb.coef[t] = cf[t]; }
  int pos = 0;
  for (int o = 0; o < DIM; ++o) {
    tb.o_start[o] = pos;
    for (int t = 0; t < T; ++t)
      if (out_idx[t] == o) { tb.e_in[pos] = in_idx[t]; tb.e_t[pos] = t; ++pos; }
  }
  tb.o_start[DIM] = pos;
  return tb;
}

__constant__ Tables TAB = build_tables();

// ---------------- helpers ----------------------------------------------------
__device__ __forceinline__ uint16_t f2bf(float f) {
  uint32_t u = __float_as_uint(f);
  uint32_t r = (u + 0x7FFFu + ((u >> 16) & 1u)) >> 16;
  return (uint16_t)r;
}

__device__ __forceinline__ void load_lds16(const void* g, void* l) {
  __builtin_amdgcn_global_load_lds(
      (const __attribute__((address_space(1))) uint32_t*)g,
      (__attribute__((address_space(3))) uint32_t*)l, 16, 0, 0);
}

typedef __bf16 v8bf __attribute__((ext_vector_type(8)));
typedef float  v4f  __attribute__((ext_vector_type(4)));

// ---------------- kernel 1: fused prep ---------------------------------------
// blocks [0, NCVT): fp32 -> bf16 cast of input (float4 per thread)
// blocks [NCVT, NCVT+580): LDS-tiled transpose of weights:
//   Bt[t][d][c] = coef[t] * W[w_idx[t]][c][d], 4 blocks per t (32 d each)
#define NCVT (NROWS * DIM * CIN / 4 / 256)   // 25600 blocks
#define NWB  (145 * 4)

__global__ void prep_kernel(const float* __restrict__ X, uint16_t* __restrict__ Y,
                            const float* __restrict__ W, uint16_t* __restrict__ Bt) {
  if (blockIdx.x < NCVT) {
    int i = blockIdx.x * 256 + threadIdx.x;
    float4 v = ((const float4*)X)[i];
    ushort4 o;
    o.x = f2bf(v.x); o.y = f2bf(v.y); o.z = f2bf(v.z); o.w = f2bf(v.w);
    ((ushort4*)Y)[i] = o;
  } else {
    __shared__ float tile[128][33];
    int b  = blockIdx.x - NCVT;
    int t  = b >> 2;
    int d0 = (b & 3) << 5;                  // 32 d-values per block
    int w  = TAB.w_idx[t];
    float cf = TAB.coef[t];
    const float* Wp = W + (size_t)w * CIN * COUT;
    uint16_t* Bp = Bt + (size_t)t * CIN * COUT;
    int tid = threadIdx.x;
    // read: coalesced 32-float (128B) rows of W[c][d0..d0+31]
    {
      int dcol = tid & 31, cbase = tid >> 5;     // 8 c-rows per pass
      #pragma unroll
      for (int r = 0; r < 16; ++r) {
        int c = (r << 3) + cbase;
        tile[c][dcol] = cf * Wp[(size_t)c * COUT + d0 + dcol];
      }
    }
    __syncthreads();
    // write: coalesced bf16 rows of Bt[t][d][c] (c contiguous)
    {
      int c = tid & 127, dbase = tid >> 7;       // 2 d-rows per pass
      #pragma unroll
      for (int r = 0; r < 16; ++r) {
        int dd = (r << 1) + dbase;
        Bp[(size_t)(d0 + dd) * CIN + c] = f2bf(tile[c][dd]);
      }
    }
  }
}

// ---------------- kernel 2: main GEMM ----------------------------------------
// Per block: output tile Out[n0..n0+127][o][0..127] = sum over entries e of
//   Xb[n][IN[e]][:] (128 ch) . Bt[e_t][:][:]  (K = 128*nE)
// m97 structure: 128x128 tile, 4 waves, BK=64, global_load_lds(16B),
// XOR chunk swizzle so ds_read_b128 frag loads are <=2-way bank conflicted.
// Grid is 1-D with XCD-aware swizzle: XCD = lb&7 gets 8 whole n-tiles; the
// 25 o-blocks of one n-tile run consecutively on one XCD so the 0.8 MB A slab
// is fetched once into that XCD's L2 and reused 25x.
__global__ __launch_bounds__(256) void so2_gemm(
    const uint16_t* __restrict__ Xb,   // [NROWS][DIM][CIN] bf16 bits
    const uint16_t* __restrict__ Bt,   // [T][COUT][CIN]    bf16 bits
    float* __restrict__ Out) {         // [NROWS][DIM][COUT]
  __shared__ __align__(16) uint16_t As[128 * 64];
  __shared__ __align__(16) uint16_t Bs[128 * 64];

  // XCD-aware decode: lb -> (o, n-tile)
  const int lb   = blockIdx.x;            // 0..1599
  const int xcd  = lb & 7;
  const int slot = lb >> 3;               // 0..199
  const int o    = slot % 25;             // o sweeps fastest within an XCD
  const int nt   = xcd + ((slot / 25) << 3);
  const int n0   = nt << 7;

  const int e0 = TAB.o_start[o];
  const int nE = TAB.o_start[o + 1] - e0;

  const int tid  = threadIdx.x;
  const int w    = tid >> 6;
  const int l    = tid & 63;

  // staging geometry: per issue j, rows m = j*32 + srow, LDS slot = l%8,
  // global source chunk = slot ^ (m%8)   (m%8 == l>>3 here)
  const int srow = (w << 3) + (l >> 3);          // 0..31
  const int slt  = l & 7;
  const int ssrc = ((slt ^ (l >> 3)) << 3);      // element offset 0..56

  // compute geometry
  const int lr   = l & 15;
  const int quad = l >> 4;
  const int wr   = (w & 1) << 6;
  const int wc   = (w >> 1) << 6;

  v4f acc[4][4];
  #pragma unroll
  for (int i = 0; i < 4; ++i)
    #pragma unroll
    for (int j = 0; j < 4; ++j)
      acc[i][j] = v4f{0.f, 0.f, 0.f, 0.f};

  const int nIter = nE << 1;
  for (int ki = 0; ki < nIter; ++ki) {
    const int e    = e0 + (ki >> 1);
    const int kk   = (ki & 1) << 6;            // channel half: 0 or 64
    const int irow = TAB.e_in[e];
    const int trow = TAB.e_t[e];

    const uint16_t* gA = Xb + ((size_t)(n0 + srow) * DIM + irow) * CIN + kk + ssrc;
    const uint16_t* gB = Bt + ((size_t)trow * COUT + srow) * CIN + kk + ssrc;

    if (ki) __syncthreads();                    // prev compute done reading LDS
    #pragma unroll
    for (int j = 0; j < 4; ++j) {
      const int m = (j << 5) + srow;
      load_lds16(gA + (size_t)(j << 5) * (DIM * CIN), &As[m * 64 + slt * 8]);
      load_lds16(gB + (size_t)(j << 5) * CIN,         &Bs[m * 64 + slt * 8]);
    }
    __syncthreads();                            // staging visible

    #pragma unroll
    for (int kk2 = 0; kk2 < 2; ++kk2) {
      const int s = (((kk2 << 2) + quad) ^ (lr & 7)) << 3;
      v8bf a[4], b[4];
      #pragma unroll
      for (int i = 0; i < 4; ++i) {
        a[i] = *(const v8bf*)(&As[(wr + (i << 4) + lr) * 64 + s]);
        b[i] = *(const v8bf*)(&Bs[(wc + (i << 4) + lr) * 64 + s]);
      }
      #pragma unroll
      for (int i = 0; i < 4; ++i)
        #pragma unroll
        for (int j = 0; j < 4; ++j)
          acc[i][j] = __builtin_amdgcn_mfma_f32_16x16x32_bf16(a[i], b[j],
                                                              acc[i][j], 0, 0, 0);
    }
  }

  // epilogue: C/D layout col = lane&15 (d), row = quad*4 + r (n)
  #pragma unroll
  for (int i = 0; i < 4; ++i) {
    #pragma unroll
    for (int r = 0; r < 4; ++r) {
      const int n = n0 + wr + (i << 4) + (quad << 2) + r;
      float* op = Out + ((size_t)n * DIM + o) * COUT + wc + lr;
      #pragma unroll
      for (int j = 0; j < 4; ++j)
        op[j << 4] = acc[i][j][r];
    }
  }
}

// ---------------- launcher ---------------------------------------------------
extern "C" void kernel_launch(void* const* d_in, const int* in_sizes, int n_in,
                              void* d_out, int out_size, void* d_ws, size_t ws_size,
                              hipStream_t stream) {
  const float* X = (const float*)d_in[0];   // [8192][25][128]
  const float* W = (const float*)d_in[1];   // [85][128][128]
  float* Out = (float*)d_out;

  uint16_t* Xb = (uint16_t*)d_ws;                                   // 52.4 MB
  uint16_t* Bt = (uint16_t*)((char*)d_ws + (size_t)NROWS * DIM * CIN * 2);  // 4.75 MB

  // 1) fused prep: input fp32->bf16 cast + LDS-tiled weight transpose
  prep_kernel<<<NCVT + NWB, 256, 0, stream>>>(X, Xb, W, Bt);
  // 2) grouped GEMM, XCD-swizzled 1-D grid
  so2_gemm<<<DIM * (NROWS / 128), 256, 0, stream>>>(Xb, Bt, Out);
}